// Round 1
// baseline (762.686 us; speedup 1.0000x reference)
//
#include <hip/hip_runtime.h>
#include <hip/hip_cooperative_groups.h>
#include <stdint.h>

namespace cg = cooperative_groups;

#define N 8192
#define IN_F 512
#define OUT_F 128
#define NCLS 10
#define ALPHA 0.2f

// attention tiling
#define SPLIT 4
#define BM 32
#define BK 256
#define ASTR 264                  // 256 + 8 shorts pad
#define NIT (N / (BK * SPLIT))    // 8 j-iterations per block

// Wh tiling
#define WH_ROWS 16
#define WH_STR 520                // 512 + 8 shorts pad: frag reads 2-way (free)

#define GRID_BLKS 1024            // 4 blocks/CU x 256 CUs, exact capacity

typedef float f32x4 __attribute__((ext_vector_type(4)));
typedef int   i32x4 __attribute__((ext_vector_type(4)));
typedef short s16x4 __attribute__((ext_vector_type(4)));
typedef short s16x8 __attribute__((ext_vector_type(8)));

__device__ __forceinline__ short f2bf(float x) {
    unsigned u = __builtin_bit_cast(unsigned, x);
    u = (u + 0x7FFFu + ((u >> 16) & 1u)) >> 16;  // RNE
    return (short)u;
}
__device__ __forceinline__ float bf2f(short s) {
    unsigned u = ((unsigned)(unsigned short)s) << 16;
    return __builtin_bit_cast(float, u);
}

// ---------------------------------------------------------------------------
// Fused cooperative kernel: 4 phases, 3 grid syncs, one dispatch.
// LDS union (33792 B = attn tile, the max):
//   phase1: Ahi [0,16640) | Alo [16640,33280) ; whs overlays [0,8448) after bar
//   phase2: As[2][32][264] shorts = 33792 B
//   phase3: hu [0,8448)
// ---------------------------------------------------------------------------
__global__ __launch_bounds__(256, 4)
void gat_fused(const float* __restrict__ h, const int* __restrict__ dist,
               const float* __restrict__ W, const float* __restrict__ a,
               const float* __restrict__ Wc, const float* __restrict__ bc,
               float* __restrict__ out,
               short* __restrict__ WhT, short* __restrict__ WThi,
               short* __restrict__ WTlo, float* __restrict__ Wh1,
               float* __restrict__ Wh2, float* __restrict__ acc_part,
               float* __restrict__ l_part)
{
    cg::grid_group grid = cg::this_grid();
    __shared__ __align__(16) char smem[2 * BM * ASTR * 2];   // 33792 B
    const int t = threadIdx.x;
    const int b = blockIdx.x;

    // ---------------- phase 0: split W -> bf16 hi/lo, fragment-blocked layout
    if (b < 256) {
        int idx = b * 256 + t;                    // 512*128 = 65536
        int k = idx >> 7, col = idx & 127;
        float x = W[idx];
        short hi = f2bf(x);
        short lo = f2bf(x - bf2f(hi));
        size_t ao = (size_t)(k >> 5) * (128 * 32) + (size_t)col * 32 + (k & 31);
        WThi[ao] = hi;
        WTlo[ao] = lo;
    }
    grid.sync();

    // ---------------- phase 1: Wh = h @ W (split-bf16, 3 MFMA products)
    if (b < 512) {
        short (*Ahi)[WH_STR] = (short (*)[WH_STR])(smem);
        short (*Alo)[WH_STR] = (short (*)[WH_STR])(smem + WH_ROWS * WH_STR * 2);
        float (*whs)[OUT_F + 4] = (float (*)[OUT_F + 4])(smem);  // overlays Ahi

        const int r0 = b * WH_ROWS;
        {   // stage h tile [16][512] as bf16 hi/lo (32B/lane coalesced)
            int row = t >> 4, c4 = t & 15;
            const float* hrow = h + (size_t)(r0 + row) * IN_F;
            #pragma unroll
            for (int jj = 0; jj < 4; ++jj) {
                int k0 = c4 * 8 + jj * 128;
                f32x4 x0 = *(const f32x4*)(hrow + k0);
                f32x4 x1 = *(const f32x4*)(hrow + k0 + 4);
                s16x8 hi, lo;
                #pragma unroll
                for (int e = 0; e < 4; ++e) {
                    short h0 = f2bf(x0[e]); hi[e] = h0; lo[e] = f2bf(x0[e] - bf2f(h0));
                    short h1 = f2bf(x1[e]); hi[4 + e] = h1; lo[4 + e] = f2bf(x1[e] - bf2f(h1));
                }
                *(s16x8*)&Ahi[row][k0] = hi;
                *(s16x8*)&Alo[row][k0] = lo;
            }
        }
        __syncthreads();

        const int lane = t & 63, w = t >> 6;
        const int q = lane >> 4, ln16 = lane & 15;
        f32x4 acc[2] = {};
        #pragma unroll
        for (int kc = 0; kc < IN_F / 32; ++kc) {
            s16x8 ahi = *(const s16x8*)&Ahi[ln16][kc * 32 + q * 8];
            s16x8 alo = *(const s16x8*)&Alo[ln16][kc * 32 + q * 8];
            #pragma unroll
            for (int nt = 0; nt < 2; ++nt) {
                int col = w * 32 + nt * 16 + ln16;
                size_t boff = (size_t)kc * 4096 + (size_t)col * 32 + q * 8;
                s16x8 bhi = *(const s16x8*)(WThi + boff);
                s16x8 blo = *(const s16x8*)(WTlo + boff);
                acc[nt] = __builtin_amdgcn_mfma_f32_16x16x32_bf16(ahi, bhi, acc[nt], 0, 0, 0);
                acc[nt] = __builtin_amdgcn_mfma_f32_16x16x32_bf16(ahi, blo, acc[nt], 0, 0, 0);
                acc[nt] = __builtin_amdgcn_mfma_f32_16x16x32_bf16(alo, bhi, acc[nt], 0, 0, 0);
            }
        }
        __syncthreads();   // Ahi/Alo dead everywhere: whs may overlay
        #pragma unroll
        for (int nt = 0; nt < 2; ++nt)
            #pragma unroll
            for (int reg = 0; reg < 4; ++reg)
                whs[q * 4 + reg][w * 32 + nt * 16 + ln16] = acc[nt][reg];
        __syncthreads();

        // Wh1/Wh2: 16 rows, 8 threads per row
        if (t < 128) {
            int r = t >> 3, s = t & 7;
            float s1 = 0.f, s2 = 0.f;
            #pragma unroll
            for (int cc = 0; cc < 16; ++cc) {
                int c = s * 16 + cc;
                float v = whs[r][c];
                s1 = fmaf(v, a[c], s1);
                s2 = fmaf(v, a[OUT_F + c], s2);
            }
            s1 += __shfl_xor(s1, 1); s1 += __shfl_xor(s1, 2); s1 += __shfl_xor(s1, 4);
            s2 += __shfl_xor(s2, 1); s2 += __shfl_xor(s2, 2); s2 += __shfl_xor(s2, 4);
            if (s == 0) { Wh1[r0 + r] = s1; Wh2[r0 + r] = s2; }
        }
        // WhT bf16, fragment-blocked: idx = (j>>5)*4096 + col*32 + (j&31)
        {
            int c = t >> 1, h8 = t & 1;
            s16x8 pack;
            #pragma unroll
            for (int rr = 0; rr < 8; ++rr) pack[rr] = f2bf(whs[h8 * 8 + rr][c]);
            size_t addr = (size_t)(r0 >> 5) * 4096 + (size_t)c * 32 + (r0 & 16) + h8 * 8;
            *(s16x8*)(WhT + addr) = pack;
        }
    }
    grid.sync();

    // ---------------- phase 2: masked-softmax attention + PV, j-split
    {
        short (*As)[BM][ASTR] = (short (*)[BM][ASTR])smem;
        const int it = b & 255;
        const int sp = b >> 8;
        const int i0 = it * BM;
        const int r = t >> 3, s = t & 7;       // p-phase: row r, j-slice s
        const int lane = t & 63, w = t >> 6;   // mfma-phase
        const int q = lane >> 4, ln16 = lane & 15;
        const int j0 = sp * (NIT * BK);

        const int* __restrict__ drow = dist + (size_t)(i0 + r) * N + j0;
        const float* __restrict__ wh2p = Wh2 + j0;
        const float wh1 = Wh1[i0 + r];
        float l_acc = 0.f;
        f32x4 acc[2][2] = {};

        i32x4 d[8];
        #pragma unroll
        for (int u = 0; u < 8; ++u) d[u] = *(const i32x4*)(drow + u * 32 + s * 4);

        for (int kt = 0; kt < NIT; ++kt) {
            const int jb = kt * BK;
            const bool more = (kt + 1) < NIT;
            i32x4 dn[8];
            if (more) {   // register prefetch of next dist tile
                #pragma unroll
                for (int u = 0; u < 8; ++u)
                    dn[u] = *(const i32x4*)(drow + jb + BK + u * 32 + s * 4);
            }
            short* arow = &As[kt & 1][r][0];
            #pragma unroll
            for (int u = 0; u < 8; ++u) {
                f32x4 w2 = *(const f32x4*)(wh2p + jb + u * 32 + s * 4);
                s16x4 pk;
                #pragma unroll
                for (int e = 0; e < 4; ++e) {
                    float sv = wh1 + w2[e];
                    float lr = fmaxf(sv, ALPHA * sv);
                    float pv = (d[u][e] > 0) ? __expf(lr) : 0.f;
                    l_acc += pv;
                    pk[e] = f2bf(pv);
                }
                *(s16x4*)(arow + u * 32 + s * 4) = pk;
            }
            __syncthreads();
            const short* ab = &As[kt & 1][0][0];
            const short* bbase = WhT + (size_t)(j0 + jb) * 128;   // blocked layout
            #pragma unroll
            for (int kc = 0; kc < BK / 32; ++kc) {
                s16x8 a0 = *(const s16x8*)(ab + ln16 * ASTR + kc * 32 + q * 8);
                s16x8 a1 = *(const s16x8*)(ab + (16 + ln16) * ASTR + kc * 32 + q * 8);
                #pragma unroll
                for (int nt = 0; nt < 2; ++nt) {
                    int col = w * 32 + nt * 16 + ln16;
                    s16x8 bb = *(const s16x8*)(bbase + (size_t)kc * 4096 + col * 32 + q * 8);
                    acc[0][nt] = __builtin_amdgcn_mfma_f32_16x16x32_bf16(a0, bb, acc[0][nt], 0, 0, 0);
                    acc[1][nt] = __builtin_amdgcn_mfma_f32_16x16x32_bf16(a1, bb, acc[1][nt], 0, 0, 0);
                }
            }
            if (more) {
                #pragma unroll
                for (int u = 0; u < 8; ++u) d[u] = dn[u];
            }
        }

        // partial row sums
        l_acc += __shfl_xor(l_acc, 1);
        l_acc += __shfl_xor(l_acc, 2);
        l_acc += __shfl_xor(l_acc, 4);
        if (s == 0) l_part[(size_t)sp * N + i0 + r] = l_acc;

        // partial acc (C/D: col=lane&15, row=q*4+reg)
        float* ap = acc_part + (size_t)sp * N * OUT_F + (size_t)i0 * OUT_F;
        #pragma unroll
        for (int mt = 0; mt < 2; ++mt)
            #pragma unroll
            for (int reg = 0; reg < 4; ++reg) {
                int row = mt * 16 + q * 4 + reg;
                #pragma unroll
                for (int nt = 0; nt < 2; ++nt)
                    ap[(size_t)row * OUT_F + w * 32 + nt * 16 + ln16] = acc[mt][nt][reg];
            }
    }
    grid.sync();

    // ---------------- phase 3: reduce partials, softmax-div, elu, classifier
    if (b < 512) {
        float (*hu)[OUT_F + 4] = (float (*)[OUT_F + 4])smem;
        const int i0 = b * 16;
        const int row = t >> 4, cg4 = t & 15;

        f32x4 v0 = {0.f, 0.f, 0.f, 0.f}, v1 = {0.f, 0.f, 0.f, 0.f};
        float l = 0.f;
        for (int s = 0; s < SPLIT; ++s) {
            const float* ap = acc_part + (size_t)s * N * OUT_F + (size_t)(i0 + row) * OUT_F + cg4 * 8;
            v0 += *(const f32x4*)ap;
            v1 += *(const f32x4*)(ap + 4);
            l += l_part[(size_t)s * N + i0 + row];
        }
        float inv = 1.f / l;
        #pragma unroll
        for (int e = 0; e < 4; ++e) {
            float x0 = v0[e] * inv; x0 = x0 > 0.f ? x0 : (__expf(x0) - 1.f);
            float x1 = v1[e] * inv; x1 = x1 > 0.f ? x1 : (__expf(x1) - 1.f);
            hu[row][cg4 * 8 + e] = x0;
            hu[row][cg4 * 8 + 4 + e] = x1;
        }
        __syncthreads();

        if (t < 16 * NCLS) {
            int rr = t / NCLS, cls = t - rr * NCLS;
            const f32x4* hurow = (const f32x4*)&hu[rr][0];
            const f32x4* wcrow = (const f32x4*)(Wc + cls * OUT_F);
            float sum = bc[cls];
            #pragma unroll 8
            for (int c4 = 0; c4 < OUT_F / 4; ++c4) {
                f32x4 hv = hurow[c4];
                f32x4 wv = wcrow[c4];
                sum += hv[0] * wv[0] + hv[1] * wv[1] + hv[2] * wv[2] + hv[3] * wv[3];
            }
            out[(size_t)(i0 + rr) * NCLS + cls] = sum;
        }
    }
}

// ===========================================================================
// Fallback path: the proven 4-kernel pipeline (used only if the cooperative
// launch is rejected by the runtime).
// ===========================================================================
__global__ void split_w_kernel(const float* __restrict__ W,
                               short* __restrict__ WThi, short* __restrict__ WTlo) {
    int idx = blockIdx.x * 256 + threadIdx.x;
    int k = idx >> 7, col = idx & 127;
    float x = W[idx];
    short hi = f2bf(x);
    short lo = f2bf(x - bf2f(hi));
    size_t ao = (size_t)(k >> 5) * (128 * 32) + (size_t)col * 32 + (k & 31);
    WThi[ao] = hi;
    WTlo[ao] = lo;
}

__global__ __launch_bounds__(256, 2)
void wh_kernel(const float* __restrict__ h, const short* __restrict__ WThi,
               const short* __restrict__ WTlo, const float* __restrict__ a,
               short* __restrict__ WhT, float* __restrict__ Wh1,
               float* __restrict__ Wh2) {
    __shared__ __align__(16) short Ahi[WH_ROWS][WH_STR];
    __shared__ __align__(16) short Alo[WH_ROWS][WH_STR];
    __shared__ __align__(16) float whs[WH_ROWS][OUT_F + 4];

    const int t = threadIdx.x;
    const int r0 = blockIdx.x * WH_ROWS;

    {
        int row = t >> 4, c4 = t & 15;
        const float* hrow = h + (size_t)(r0 + row) * IN_F;
        #pragma unroll
        for (int jj = 0; jj < 4; ++jj) {
            int k0 = c4 * 8 + jj * 128;
            f32x4 x0 = *(const f32x4*)(hrow + k0);
            f32x4 x1 = *(const f32x4*)(hrow + k0 + 4);
            s16x8 hi, lo;
            #pragma unroll
            for (int e = 0; e < 4; ++e) {
                short h0 = f2bf(x0[e]); hi[e] = h0; lo[e] = f2bf(x0[e] - bf2f(h0));
                short h1 = f2bf(x1[e]); hi[4 + e] = h1; lo[4 + e] = f2bf(x1[e] - bf2f(h1));
            }
            *(s16x8*)&Ahi[row][k0] = hi;
            *(s16x8*)&Alo[row][k0] = lo;
        }
    }
    __syncthreads();

    const int lane = t & 63, w = t >> 6;
    const int q = lane >> 4, ln16 = lane & 15;
    f32x4 acc[2] = {};
    #pragma unroll
    for (int kc = 0; kc < IN_F / 32; ++kc) {
        s16x8 ahi = *(const s16x8*)&Ahi[ln16][kc * 32 + q * 8];
        s16x8 alo = *(const s16x8*)&Alo[ln16][kc * 32 + q * 8];
        #pragma unroll
        for (int nt = 0; nt < 2; ++nt) {
            int col = w * 32 + nt * 16 + ln16;
            size_t boff = (size_t)kc * 4096 + (size_t)col * 32 + q * 8;
            s16x8 bhi = *(const s16x8*)(WThi + boff);
            s16x8 blo = *(const s16x8*)(WTlo + boff);
            acc[nt] = __builtin_amdgcn_mfma_f32_16x16x32_bf16(ahi, bhi, acc[nt], 0, 0, 0);
            acc[nt] = __builtin_amdgcn_mfma_f32_16x16x32_bf16(ahi, blo, acc[nt], 0, 0, 0);
            acc[nt] = __builtin_amdgcn_mfma_f32_16x16x32_bf16(alo, bhi, acc[nt], 0, 0, 0);
        }
    }
    #pragma unroll
    for (int nt = 0; nt < 2; ++nt)
        #pragma unroll
        for (int reg = 0; reg < 4; ++reg)
            whs[q * 4 + reg][w * 32 + nt * 16 + ln16] = acc[nt][reg];
    __syncthreads();

    if (t < 128) {
        int r = t >> 3, s = t & 7;
        float s1 = 0.f, s2 = 0.f;
        #pragma unroll
        for (int cc = 0; cc < 16; ++cc) {
            int c = s * 16 + cc;
            float v = whs[r][c];
            s1 = fmaf(v, a[c], s1);
            s2 = fmaf(v, a[OUT_F + c], s2);
        }
        s1 += __shfl_xor(s1, 1); s1 += __shfl_xor(s1, 2); s1 += __shfl_xor(s1, 4);
        s2 += __shfl_xor(s2, 1); s2 += __shfl_xor(s2, 2); s2 += __shfl_xor(s2, 4);
        if (s == 0) { Wh1[r0 + r] = s1; Wh2[r0 + r] = s2; }
    }
    {
        int c = t >> 1, h8 = t & 1;
        s16x8 pack;
        #pragma unroll
        for (int rr = 0; rr < 8; ++rr) pack[rr] = f2bf(whs[h8 * 8 + rr][c]);
        size_t addr = (size_t)(r0 >> 5) * 4096 + (size_t)c * 32 + (r0 & 16) + h8 * 8;
        *(s16x8*)(WhT + addr) = pack;
    }
}

__global__ __launch_bounds__(256, 4)
void attn_kernel(const int* __restrict__ dist, const short* __restrict__ WhT,
                 const float* __restrict__ Wh1v, const float* __restrict__ Wh2v,
                 float* __restrict__ acc_part, float* __restrict__ l_part,
                 int nit) {
    __shared__ __align__(16) short As[2][BM][ASTR];

    const int t = threadIdx.x;
    const int it = blockIdx.x & 255;
    const int sp = blockIdx.x >> 8;
    const int i0 = it * BM;
    const int r = t >> 3, s = t & 7;
    const int lane = t & 63, w = t >> 6;
    const int q = lane >> 4, ln16 = lane & 15;
    const int j0 = sp * nit * BK;

    const int* __restrict__ drow = dist + (size_t)(i0 + r) * N + j0;
    const float* __restrict__ wh2p = Wh2v + j0;
    const float wh1 = Wh1v[i0 + r];
    float l_acc = 0.f;
    f32x4 acc[2][2] = {};

    i32x4 d[8];
    #pragma unroll
    for (int u = 0; u < 8; ++u) d[u] = *(const i32x4*)(drow + u * 32 + s * 4);

    for (int kt = 0; kt < nit; ++kt) {
        const int jb = kt * BK;
        const bool more = (kt + 1) < nit;
        i32x4 dn[8];
        if (more) {
            #pragma unroll
            for (int u = 0; u < 8; ++u)
                dn[u] = *(const i32x4*)(drow + jb + BK + u * 32 + s * 4);
        }
        short* arow = &As[kt & 1][r][0];
        #pragma unroll
        for (int u = 0; u < 8; ++u) {
            f32x4 w2 = *(const f32x4*)(wh2p + jb + u * 32 + s * 4);
            s16x4 pk;
            #pragma unroll
            for (int e = 0; e < 4; ++e) {
                float sv = wh1 + w2[e];
                float lr = fmaxf(sv, ALPHA * sv);
                float pv = (d[u][e] > 0) ? __expf(lr) : 0.f;
                l_acc += pv;
                pk[e] = f2bf(pv);
            }
            *(s16x4*)(arow + u * 32 + s * 4) = pk;
        }
        __syncthreads();
        const short* ab = &As[kt & 1][0][0];
        const short* bbase = WhT + (size_t)(j0 + jb) * 128;
        #pragma unroll
        for (int kc = 0; kc < BK / 32; ++kc) {
            s16x8 a0 = *(const s16x8*)(ab + ln16 * ASTR + kc * 32 + q * 8);
            s16x8 a1 = *(const s16x8*)(ab + (16 + ln16) * ASTR + kc * 32 + q * 8);
            #pragma unroll
            for (int nt = 0; nt < 2; ++nt) {
                int col = w * 32 + nt * 16 + ln16;
                s16x8 bb = *(const s16x8*)(bbase + (size_t)kc * 4096 + col * 32 + q * 8);
                acc[0][nt] = __builtin_amdgcn_mfma_f32_16x16x32_bf16(a0, bb, acc[0][nt], 0, 0, 0);
                acc[1][nt] = __builtin_amdgcn_mfma_f32_16x16x32_bf16(a1, bb, acc[1][nt], 0, 0, 0);
            }
        }
        if (more) {
            #pragma unroll
            for (int u = 0; u < 8; ++u) d[u] = dn[u];
        }
    }

    l_acc += __shfl_xor(l_acc, 1);
    l_acc += __shfl_xor(l_acc, 2);
    l_acc += __shfl_xor(l_acc, 4);
    if (s == 0) l_part[(size_t)sp * N + i0 + r] = l_acc;

    float* ap = acc_part + (size_t)sp * N * OUT_F + (size_t)i0 * OUT_F;
    #pragma unroll
    for (int mt = 0; mt < 2; ++mt)
        #pragma unroll
        for (int reg = 0; reg < 4; ++reg) {
            int row = mt * 16 + q * 4 + reg;
            #pragma unroll
            for (int nt = 0; nt < 2; ++nt)
                ap[(size_t)row * OUT_F + w * 32 + nt * 16 + ln16] = acc[mt][nt][reg];
        }
}

__global__ __launch_bounds__(256, 4)
void reduce_kernel(const float* __restrict__ acc_part, const float* __restrict__ l_part,
                   const float* __restrict__ Wc, const float* __restrict__ bcv,
                   float* __restrict__ out, int split) {
    __shared__ __align__(16) float hu[16][OUT_F + 4];
    const int t = threadIdx.x;
    const int i0 = blockIdx.x * 16;
    const int row = t >> 4, cg4 = t & 15;

    f32x4 v0 = {0.f, 0.f, 0.f, 0.f}, v1 = {0.f, 0.f, 0.f, 0.f};
    float l = 0.f;
    for (int s = 0; s < split; ++s) {
        const float* ap = acc_part + (size_t)s * N * OUT_F + (size_t)(i0 + row) * OUT_F + cg4 * 8;
        v0 += *(const f32x4*)ap;
        v1 += *(const f32x4*)(ap + 4);
        l += l_part[(size_t)s * N + i0 + row];
    }
    float inv = 1.f / l;
    #pragma unroll
    for (int e = 0; e < 4; ++e) {
        float x0 = v0[e] * inv; x0 = x0 > 0.f ? x0 : (__expf(x0) - 1.f);
        float x1 = v1[e] * inv; x1 = x1 > 0.f ? x1 : (__expf(x1) - 1.f);
        hu[row][cg4 * 8 + e] = x0;
        hu[row][cg4 * 8 + 4 + e] = x1;
    }
    __syncthreads();

    if (t < 16 * NCLS) {
        int rr = t / NCLS, cls = t - rr * NCLS;
        const f32x4* hurow = (const f32x4*)&hu[rr][0];
        const f32x4* wcrow = (const f32x4*)(Wc + cls * OUT_F);
        float sum = bcv[cls];
        #pragma unroll 8
        for (int c4 = 0; c4 < OUT_F / 4; ++c4) {
            f32x4 hv = hurow[c4];
            f32x4 wv = wcrow[c4];
            sum += hv[0] * wv[0] + hv[1] * wv[1] + hv[2] * wv[2] + hv[3] * wv[3];
        }
        out[(size_t)(i0 + rr) * NCLS + cls] = sum;
    }
}

// ---------------------------------------------------------------------------
extern "C" void kernel_launch(void* const* d_in, const int* in_sizes, int n_in,
                              void* d_out, int out_size, void* d_ws, size_t ws_size,
                              hipStream_t stream) {
    const float* h    = (const float*)d_in[0];
    const int*   dist = (const int*)d_in[1];
    const float* W    = (const float*)d_in[2];
    const float* a    = (const float*)d_in[3];
    const float* Wc   = (const float*)d_in[4];
    const float* bc   = (const float*)d_in[5];
    float* out = (float*)d_out;

    char* ws = (char*)d_ws;
    size_t off = 0;
    short* WhT  = (short*)(ws + off); off += (size_t)OUT_F * N * 2;     // 2 MB
    short* WThi = (short*)(ws + off); off += (size_t)IN_F * OUT_F * 2;  // 128 KB
    short* WTlo = (short*)(ws + off); off += (size_t)IN_F * OUT_F * 2;  // 128 KB
    float* Wh1  = (float*)(ws + off); off += (size_t)N * 4;
    float* Wh2  = (float*)(ws + off); off += (size_t)N * 4;

    size_t per_split = (size_t)N * OUT_F * 4 + (size_t)N * 4;
    int split = SPLIT;
    if (off + 4 * per_split > ws_size) split = 2;
    if (off + 2 * per_split > ws_size) split = 1;
    float* acc_part = (float*)(ws + off); off += (size_t)split * N * OUT_F * 4;
    float* l_part   = (float*)(ws + off);

    hipError_t rc = hipErrorUnknown;
    if (split == SPLIT) {
        void* args[] = { (void*)&h, (void*)&dist, (void*)&W, (void*)&a,
                         (void*)&Wc, (void*)&bc, (void*)&out,
                         (void*)&WhT, (void*)&WThi, (void*)&WTlo,
                         (void*)&Wh1, (void*)&Wh2, (void*)&acc_part, (void*)&l_part };
        rc = hipLaunchCooperativeKernel((const void*)gat_fused, dim3(GRID_BLKS),
                                        dim3(256), args, 0u, stream);
    }
    if (rc != hipSuccess) {
        // fallback: proven 4-kernel pipeline
        hipLaunchKernelGGL(split_w_kernel, dim3(256), dim3(256), 0, stream, W, WThi, WTlo);
        hipLaunchKernelGGL(wh_kernel, dim3(N / WH_ROWS), dim3(256), 0, stream,
                           h, WThi, WTlo, a, WhT, Wh1, Wh2);
        int nit = N / (BK * split);
        hipLaunchKernelGGL(attn_kernel, dim3(256 * split), dim3(256), 0, stream,
                           dist, WhT, Wh1, Wh2, acc_part, l_part, nit);
        hipLaunchKernelGGL(reduce_kernel, dim3(N / 16), dim3(256), 0, stream,
                           acc_part, l_part, Wc, bc, out, split);
    }
}

// Round 2
// 437.087 us; speedup vs baseline: 1.7449x; 1.7449x over previous
//
#include <hip/hip_runtime.h>
#include <stdint.h>

#define N 8192
#define IN_F 512
#define OUT_F 128
#define NCLS 10
#define ALPHA 0.2f

typedef float f32x4 __attribute__((ext_vector_type(4)));
typedef int   i32x4 __attribute__((ext_vector_type(4)));
typedef short s16x4 __attribute__((ext_vector_type(4)));
typedef short s16x8 __attribute__((ext_vector_type(8)));

__device__ __forceinline__ short f2bf(float x) {
    unsigned u = __builtin_bit_cast(unsigned, x);
    u = (u + 0x7FFFu + ((u >> 16) & 1u)) >> 16;  // RNE
    return (short)u;
}
__device__ __forceinline__ float bf2f(short s) {
    unsigned u = ((unsigned)(unsigned short)s) << 16;
    return __builtin_bit_cast(float, u);
}

// ---------------------------------------------------------------------------
// Kernel M: dist (int32, values 0/1, 268 MB) -> 1-bit adjacency mask (8 MB).
// Pure streaming: 128 B contiguous read + 4 B write per thread, no dependent
// chains -> saturates HBM. Word w = bits for j in [ (w%256)*32, +32 ) of row
// i = w/256; bit position = j%32. This is the ONLY reader of dist.
// ---------------------------------------------------------------------------
__global__ __launch_bounds__(256, 8)
void mask_kernel(const int* __restrict__ dist, unsigned* __restrict__ mask) {
    size_t w = (size_t)blockIdx.x * 256 + threadIdx.x;   // 8192*256 words total
    const int* p = dist + w * 32;
    unsigned b = 0;
    #pragma unroll
    for (int u = 0; u < 8; ++u) {
        i32x4 v = *(const i32x4*)(p + u * 4);
        #pragma unroll
        for (int e = 0; e < 4; ++e) b |= (v[e] > 0 ? 1u : 0u) << (u * 4 + e);
    }
    mask[w] = b;
}

// ---------------------------------------------------------------------------
// Kernel 0: split W [512][128] fp32 -> bf16 hi/lo in fragment-blocked layout:
// idx(col,k) = (k>>5)*(128*32) + col*32 + (k&31)
// ---------------------------------------------------------------------------
__global__ void split_w_kernel(const float* __restrict__ W,
                               short* __restrict__ WThi, short* __restrict__ WTlo) {
    int idx = blockIdx.x * 256 + threadIdx.x;       // 512*128 = 65536
    int k = idx >> 7, col = idx & 127;
    float x = W[idx];                               // row-major [k][col]
    short hi = f2bf(x);
    short lo = f2bf(x - bf2f(hi));
    size_t a = (size_t)(k >> 5) * (128 * 32) + (size_t)col * 32 + (k & 31);
    WThi[a] = hi;
    WTlo[a] = lo;
}

// ---------------------------------------------------------------------------
// Kernel 1: Wh = h@W via split-bf16 MFMA (3 products). Writes Wh1/Wh2 (fp32)
// and WhT bf16 fragment-blocked [(j>>5)][col][j&31].
// 512 blocks x 256 threads, 16 rows/block. (256,2): needs >64 VGPR.
// ---------------------------------------------------------------------------
#define WH_ROWS 16
#define WH_STR 520   // 512 + 8 shorts pad: frag reads land 2-way (free)

__global__ __launch_bounds__(256, 2)
void wh_kernel(const float* __restrict__ h, const short* __restrict__ WThi,
               const short* __restrict__ WTlo, const float* __restrict__ a,
               short* __restrict__ WhT, float* __restrict__ Wh1,
               float* __restrict__ Wh2) {
    __shared__ __align__(16) short Ahi[WH_ROWS][WH_STR];
    __shared__ __align__(16) short Alo[WH_ROWS][WH_STR];
    __shared__ __align__(16) float whs[WH_ROWS][OUT_F + 4];

    const int t = threadIdx.x;
    const int r0 = blockIdx.x * WH_ROWS;

    {   // stage h tile [16][512] as bf16 hi/lo (coalesced 32B/lane reads)
        int row = t >> 4, c4 = t & 15;
        const float* hrow = h + (size_t)(r0 + row) * IN_F;
        #pragma unroll
        for (int jj = 0; jj < 4; ++jj) {
            int k0 = c4 * 8 + jj * 128;
            f32x4 x0 = *(const f32x4*)(hrow + k0);
            f32x4 x1 = *(const f32x4*)(hrow + k0 + 4);
            s16x8 hi, lo;
            #pragma unroll
            for (int e = 0; e < 4; ++e) {
                short h0 = f2bf(x0[e]); hi[e] = h0; lo[e] = f2bf(x0[e] - bf2f(h0));
                short h1 = f2bf(x1[e]); hi[4 + e] = h1; lo[4 + e] = f2bf(x1[e] - bf2f(h1));
            }
            *(s16x8*)&Ahi[row][k0] = hi;
            *(s16x8*)&Alo[row][k0] = lo;
        }
    }
    __syncthreads();

    const int lane = t & 63, w = t >> 6;
    const int q = lane >> 4, ln16 = lane & 15;
    f32x4 acc[2] = {};
    #pragma unroll
    for (int kc = 0; kc < IN_F / 32; ++kc) {
        s16x8 ahi = *(const s16x8*)&Ahi[ln16][kc * 32 + q * 8];
        s16x8 alo = *(const s16x8*)&Alo[ln16][kc * 32 + q * 8];
        #pragma unroll
        for (int nt = 0; nt < 2; ++nt) {
            int col = w * 32 + nt * 16 + ln16;
            size_t boff = (size_t)kc * 4096 + (size_t)col * 32 + q * 8;
            s16x8 bhi = *(const s16x8*)(WThi + boff);
            s16x8 blo = *(const s16x8*)(WTlo + boff);
            acc[nt] = __builtin_amdgcn_mfma_f32_16x16x32_bf16(ahi, bhi, acc[nt], 0, 0, 0);
            acc[nt] = __builtin_amdgcn_mfma_f32_16x16x32_bf16(ahi, blo, acc[nt], 0, 0, 0);
            acc[nt] = __builtin_amdgcn_mfma_f32_16x16x32_bf16(alo, bhi, acc[nt], 0, 0, 0);
        }
    }
    #pragma unroll
    for (int nt = 0; nt < 2; ++nt)
        #pragma unroll
        for (int reg = 0; reg < 4; ++reg)
            whs[q * 4 + reg][w * 32 + nt * 16 + ln16] = acc[nt][reg];
    __syncthreads();

    // Wh1/Wh2: 16 rows, 8 threads per row
    if (t < 128) {
        int r = t >> 3, s = t & 7;
        float s1 = 0.f, s2 = 0.f;
        #pragma unroll
        for (int cc = 0; cc < 16; ++cc) {
            int c = s * 16 + cc;
            float v = whs[r][c];
            s1 = fmaf(v, a[c], s1);
            s2 = fmaf(v, a[OUT_F + c], s2);
        }
        s1 += __shfl_xor(s1, 1); s1 += __shfl_xor(s1, 2); s1 += __shfl_xor(s1, 4);
        s2 += __shfl_xor(s2, 1); s2 += __shfl_xor(s2, 2); s2 += __shfl_xor(s2, 4);
        if (s == 0) { Wh1[r0 + r] = s1; Wh2[r0 + r] = s2; }
    }

    // WhT bf16, fragment-blocked: idx = (j>>5)*4096 + col*32 + (j&31)
    {
        int c = t >> 1, h8 = t & 1;
        s16x8 pack;
        #pragma unroll
        for (int rr = 0; rr < 8; ++rr) pack[rr] = f2bf(whs[h8 * 8 + rr][c]);
        size_t addr = (size_t)(r0 >> 5) * 4096 + (size_t)c * 32 + (r0 & 16) + h8 * 8;
        *(s16x8*)(WhT + addr) = pack;
    }
}

// ---------------------------------------------------------------------------
// Kernel 2: fused masked-softmax attention + PV matmul, j-split across SPLIT
// block groups. Mask-driven: per 32-row x 256-j tile, each thread reads
// 8 mask words (32B, broadcast across the 8 threads of a row) instead of
// 128B/thread of dist. VGPR pressure: mask regs 16 vs dist-prefetch 64 ->
// no spills under the (256,4) cap.
// grid = 256 * SPLIT blocks, 256 threads (4 waves), 32 rows/block.
// ---------------------------------------------------------------------------
#define BM 32
#define BK 256
#define ASTR (BK + 8)

__global__ __launch_bounds__(256, 4)
void attn_kernel(const unsigned* __restrict__ mask, const short* __restrict__ WhT,
                 const float* __restrict__ Wh1v, const float* __restrict__ Wh2v,
                 float* __restrict__ acc_part, float* __restrict__ l_part,
                 int nit) {
    __shared__ __align__(16) short As[2][BM][ASTR];

    const int t = threadIdx.x;
    const int it = blockIdx.x & 255;
    const int sp = blockIdx.x >> 8;
    const int i0 = it * BM;
    const int r = t >> 3, s = t & 7;       // p-phase: row r, j-slice s
    const int lane = t & 63, w = t >> 6;   // mfma-phase
    const int q = lane >> 4, ln16 = lane & 15;
    const int j0 = sp * nit * BK;
    const int sh = s * 4;

    const unsigned* __restrict__ mrow = mask + (size_t)(i0 + r) * (N / 32) + (j0 >> 5);
    const float* __restrict__ wh2p = Wh2v + j0;
    const float wh1 = Wh1v[i0 + r];
    float l_acc = 0.f;
    f32x4 acc[2][2] = {};

    i32x4 m0 = *(const i32x4*)(mrow);
    i32x4 m1 = *(const i32x4*)(mrow + 4);

    for (int kt = 0; kt < nit; ++kt) {
        const int jb = kt * BK;
        const bool more = (kt + 1) < nit;
        i32x4 n0, n1;
        if (more) {   // register prefetch of next tile's mask words
            n0 = *(const i32x4*)(mrow + (kt + 1) * 8);
            n1 = *(const i32x4*)(mrow + (kt + 1) * 8 + 4);
        }
        short* arow = &As[kt & 1][r][0];
        #pragma unroll
        for (int u = 0; u < 8; ++u) {
            f32x4 w2 = *(const f32x4*)(wh2p + jb + u * 32 + sh);
            unsigned wrd = (u < 4) ? (unsigned)m0[u] : (unsigned)m1[u - 4];
            unsigned nib = (wrd >> sh) & 15u;
            s16x4 pk;
            #pragma unroll
            for (int e = 0; e < 4; ++e) {
                float sv = wh1 + w2[e];
                float lr = fmaxf(sv, ALPHA * sv);
                float pv = (nib & (1u << e)) ? __expf(lr) : 0.f;
                l_acc += pv;
                pk[e] = f2bf(pv);
            }
            *(s16x4*)(arow + u * 32 + sh) = pk;
        }
        __syncthreads();
        const short* ab = &As[kt & 1][0][0];
        const short* bbase = WhT + (size_t)(j0 + jb) * 128;   // blocked layout
        #pragma unroll
        for (int kc = 0; kc < BK / 32; ++kc) {
            s16x8 a0 = *(const s16x8*)(ab + ln16 * ASTR + kc * 32 + q * 8);
            s16x8 a1 = *(const s16x8*)(ab + (16 + ln16) * ASTR + kc * 32 + q * 8);
            #pragma unroll
            for (int nt = 0; nt < 2; ++nt) {
                int col = w * 32 + nt * 16 + ln16;
                s16x8 b = *(const s16x8*)(bbase + (size_t)kc * 4096 + col * 32 + q * 8);
                acc[0][nt] = __builtin_amdgcn_mfma_f32_16x16x32_bf16(a0, b, acc[0][nt], 0, 0, 0);
                acc[1][nt] = __builtin_amdgcn_mfma_f32_16x16x32_bf16(a1, b, acc[1][nt], 0, 0, 0);
            }
        }
        if (more) { m0 = n0; m1 = n1; }
    }

    // partial row sums
    l_acc += __shfl_xor(l_acc, 1);
    l_acc += __shfl_xor(l_acc, 2);
    l_acc += __shfl_xor(l_acc, 4);
    if (s == 0) l_part[(size_t)sp * N + i0 + r] = l_acc;

    // partial acc (C/D: col=lane&15, row=q*4+reg)
    float* ap = acc_part + (size_t)sp * N * OUT_F + (size_t)i0 * OUT_F;
    #pragma unroll
    for (int mt = 0; mt < 2; ++mt)
        #pragma unroll
        for (int reg = 0; reg < 4; ++reg) {
            int row = mt * 16 + q * 4 + reg;
            #pragma unroll
            for (int nt = 0; nt < 2; ++nt)
                ap[(size_t)row * OUT_F + w * 32 + nt * 16 + ln16] = acc[mt][nt][reg];
        }
}

// ---------------------------------------------------------------------------
// Kernel 3: reduce partials, softmax-divide, elu, classifier.
// 512 blocks x 256 threads, 16 rows/block.
// ---------------------------------------------------------------------------
__global__ __launch_bounds__(256, 4)
void reduce_kernel(const float* __restrict__ acc_part, const float* __restrict__ l_part,
                   const float* __restrict__ Wc, const float* __restrict__ bcv,
                   float* __restrict__ out, int split) {
    __shared__ __align__(16) float hu[16][OUT_F + 4];
    const int t = threadIdx.x;
    const int i0 = blockIdx.x * 16;
    const int row = t >> 4, cg = t & 15;

    f32x4 v0 = {0.f, 0.f, 0.f, 0.f}, v1 = {0.f, 0.f, 0.f, 0.f};
    float l = 0.f;
    for (int s = 0; s < split; ++s) {
        const float* ap = acc_part + (size_t)s * N * OUT_F + (size_t)(i0 + row) * OUT_F + cg * 8;
        v0 += *(const f32x4*)ap;
        v1 += *(const f32x4*)(ap + 4);
        l += l_part[(size_t)s * N + i0 + row];
    }
    float inv = 1.f / l;
    #pragma unroll
    for (int e = 0; e < 4; ++e) {
        float x0 = v0[e] * inv; x0 = x0 > 0.f ? x0 : (__expf(x0) - 1.f);
        float x1 = v1[e] * inv; x1 = x1 > 0.f ? x1 : (__expf(x1) - 1.f);
        hu[row][cg * 8 + e] = x0;
        hu[row][cg * 8 + 4 + e] = x1;
    }
    __syncthreads();

    if (t < 16 * NCLS) {
        int rr = t / NCLS, cls = t - rr * NCLS;
        const f32x4* hurow = (const f32x4*)&hu[rr][0];
        const f32x4* wcrow = (const f32x4*)(Wc + cls * OUT_F);
        float sum = bcv[cls];
        #pragma unroll 8
        for (int c4 = 0; c4 < OUT_F / 4; ++c4) {
            f32x4 hv = hurow[c4];
            f32x4 wv = wcrow[c4];
            sum += hv[0] * wv[0] + hv[1] * wv[1] + hv[2] * wv[2] + hv[3] * wv[3];
        }
        out[(size_t)(i0 + rr) * NCLS + cls] = sum;
    }
}

// ---------------------------------------------------------------------------
extern "C" void kernel_launch(void* const* d_in, const int* in_sizes, int n_in,
                              void* d_out, int out_size, void* d_ws, size_t ws_size,
                              hipStream_t stream) {
    const float* h    = (const float*)d_in[0];
    const int*   dist = (const int*)d_in[1];
    const float* W    = (const float*)d_in[2];
    const float* a    = (const float*)d_in[3];
    const float* Wc   = (const float*)d_in[4];
    const float* bc   = (const float*)d_in[5];
    float* out = (float*)d_out;

    char* ws = (char*)d_ws;
    size_t off = 0;
    short* WhT  = (short*)(ws + off); off += (size_t)OUT_F * N * 2;     // 2 MB
    short* WThi = (short*)(ws + off); off += (size_t)IN_F * OUT_F * 2;  // 128 KB
    short* WTlo = (short*)(ws + off); off += (size_t)IN_F * OUT_F * 2;  // 128 KB
    float* Wh1  = (float*)(ws + off); off += (size_t)N * 4;
    float* Wh2  = (float*)(ws + off); off += (size_t)N * 4;
    unsigned* mask = (unsigned*)(ws + off); off += (size_t)N * (N / 32) * 4; // 8 MB

    size_t per_split = (size_t)N * OUT_F * 4 + (size_t)N * 4;
    int split = 4;
    if (off + 4 * per_split > ws_size) split = 2;
    if (off + 2 * per_split > ws_size) split = 1;
    float* acc_part = (float*)(ws + off); off += (size_t)split * N * OUT_F * 4;
    float* l_part   = (float*)(ws + off);

    hipLaunchKernelGGL(mask_kernel, dim3(N * (N / 32) / 256), dim3(256), 0, stream,
                       dist, mask);
    hipLaunchKernelGGL(split_w_kernel, dim3(256), dim3(256), 0, stream, W, WThi, WTlo);
    hipLaunchKernelGGL(wh_kernel, dim3(N / WH_ROWS), dim3(256), 0, stream,
                       h, WThi, WTlo, a, WhT, Wh1, Wh2);
    int nit = N / (BK * split);
    hipLaunchKernelGGL(attn_kernel, dim3(256 * split), dim3(256), 0, stream,
                       mask, WhT, Wh1, Wh2, acc_part, l_part, nit);
    hipLaunchKernelGGL(reduce_kernel, dim3(N / 16), dim3(256), 0, stream,
                       acc_part, l_part, Wc, bc, out, split);
}